// Round 10
// baseline (153.136 us; speedup 1.0000x reference)
//
#include <hip/hip_runtime.h>

#define HW    3136   // 56*56
#define HW4   784    // float4 per row = 12*64 + 16
#define C     512
#define B     32
#define ROWS  (B * C)        // 16384
#define RPB   8              // rows per block
#define NBLK  (ROWS / RPB)   // 2048 blocks (completed fine in round 7)
#define JPB   (C / RPB)      // 64 blocks per batch

typedef float floatx4 __attribute__((ext_vector_type(4)));

// ws layout (zeroed on-stream each call, inside the captured graph):
//   meansbuf[(b*64+j)*8 + r] : block j of batch b publishes its 8 row-means
//   done[b*32]               : arrival counter, one 128-B line per batch
// Sync design: NO same-line RMW except the 64 arrivals per batch; polls are
// RELAXED (no cache-invalidate per poll) + s_sleep(16); every block computes
// the gate itself from published means (no aggregator, no second flag).
// Bounded spin + full self-recompute fallback => cannot hang.
__global__ __launch_bounds__(256, 8)
void se_fused_kernel(const float* __restrict__ x,
                     const float* __restrict__ W,
                     const float* __restrict__ bias,
                     float* __restrict__ meansbuf,
                     int*   __restrict__ done,
                     float* __restrict__ out) {
    const int wave = threadIdx.x >> 6;
    const int lane = threadIdx.x & 63;
    const int blk  = blockIdx.x;
    const int b    = blk >> 6;           // batch
    const int j    = blk & (JPB - 1);    // block within batch
    const int row0 = blk * RPB;
    const int m    = j >> 3;             // modality of all 8 rows

    __shared__ float lmeans[RPB];
    __shared__ int   sok;
    __shared__ float yfull[C];           // fallback only

    // ---- phase 1: means of own 8 rows (2 per wave, unrolled 12 + tail) ----
    #pragma unroll
    for (int r = 0; r < 2; ++r) {
        const int row = row0 + wave * 2 + r;
        const floatx4* xr = reinterpret_cast<const floatx4*>(x) + (size_t)row * HW4;
        float s = 0.f;
        #pragma unroll
        for (int k = 0; k < 12; ++k) {
            floatx4 v = xr[lane + 64 * k];
            s += (v.x + v.y) + (v.z + v.w);
        }
        if (lane < 16) {
            floatx4 v = xr[768 + lane];
            s += (v.x + v.y) + (v.z + v.w);
        }
        #pragma unroll
        for (int off = 32; off; off >>= 1) s += __shfl_down(s, off, 64);
        if (lane == 0) lmeans[wave * 2 + r] = s * (1.0f / HW);
    }
    __syncthreads();

    // ---- publish means (relaxed, private slots -> no RMW contention) ----
    if (threadIdx.x < RPB)
        __hip_atomic_store(&meansbuf[(size_t)(b * JPB + j) * 8 + threadIdx.x],
                           lmeans[threadIdx.x],
                           __ATOMIC_RELAXED, __HIP_MEMORY_SCOPE_AGENT);
    __syncthreads();

    // ---- arrive (release) + relaxed bounded spin ----
    if (threadIdx.x == 0) {
        __hip_atomic_fetch_add(&done[b * 32], 1,
                               __ATOMIC_RELEASE, __HIP_MEMORY_SCOPE_AGENT);
        int ok = 0;
        for (int p = 0; p < 250000; ++p) {   // ~0.43us/poll, cap ~107ms
            if (__hip_atomic_load(&done[b * 32], __ATOMIC_RELAXED,
                                  __HIP_MEMORY_SCOPE_AGENT) >= JPB) { ok = 1; break; }
            __builtin_amdgcn_s_sleep(16);
        }
        if (ok)  // acquire: synchronize-with all 64 releases
            (void)__hip_atomic_load(&done[b * 32], __ATOMIC_ACQUIRE,
                                    __HIP_MEMORY_SCOPE_AGENT);
        sok = ok;
    }
    __syncthreads();

    // ---- gate: every block computes it from published means ----
    float g;
    if (sok) {
        // lane L <-> peer block L: means of channels 8L..8L+7
        const float* mb = meansbuf + (size_t)b * JPB * 8 + lane * 8;
        const float* wm = W + m * C + lane * 8;
        float s = 0.f;
        #pragma unroll
        for (int r = 0; r < 8; ++r) s = fmaf(mb[r], wm[r], s);
        #pragma unroll
        for (int off = 32; off; off >>= 1) s += __shfl_xor(s, off, 64);
        s += bias[m];
        s = fmaxf(s, 0.f);
        g = 1.0f / (1.0f + expf(-s));
    } else {
        // fallback (pathological scheduling only): recompute batch means
        for (int c = wave; c < C; c += 4) {
            const floatx4* xr = reinterpret_cast<const floatx4*>(x)
                                + (size_t)(b * C + c) * HW4;
            float s = 0.f;
            for (int i = lane; i < HW4; i += 64) {
                floatx4 v = xr[i];
                s += (v.x + v.y) + (v.z + v.w);
            }
            #pragma unroll
            for (int off = 32; off; off >>= 1) s += __shfl_down(s, off, 64);
            if (lane == 0) yfull[c] = s * (1.0f / HW);
        }
        __syncthreads();
        const float* wm = W + m * C + lane * 8;
        float s = 0.f;
        #pragma unroll
        for (int r = 0; r < 8; ++r) s = fmaf(yfull[lane * 8 + r], wm[r], s);
        #pragma unroll
        for (int off = 32; off; off >>= 1) s += __shfl_xor(s, off, 64);
        s += bias[m];
        s = fmaxf(s, 0.f);
        g = 1.0f / (1.0f + expf(-s));
    }

    // ---- phase 2: scale own 8 rows (L3-warm re-read), nt stores ----
    #pragma unroll
    for (int r = 0; r < 2; ++r) {
        const int row = row0 + wave * 2 + r;
        const floatx4* xr  = reinterpret_cast<const floatx4*>(x) + (size_t)row * HW4;
        floatx4*      orow = reinterpret_cast<floatx4*>(out)     + (size_t)row * HW4;
        #pragma unroll
        for (int k = 0; k < 12; ++k) {
            floatx4 v = xr[lane + 64 * k];
            v *= g;
            __builtin_nontemporal_store(v, &orow[lane + 64 * k]);
        }
        if (lane < 16) {
            floatx4 v = xr[768 + lane];
            v *= g;
            __builtin_nontemporal_store(v, &orow[768 + lane]);
        }
    }
}

extern "C" void kernel_launch(void* const* d_in, const int* in_sizes, int n_in,
                              void* d_out, int out_size, void* d_ws, size_t ws_size,
                              hipStream_t stream) {
    const float* x    = (const float*)d_in[0];  // (32,512,56,56)
    const float* W    = (const float*)d_in[1];  // (8,512)
    const float* bias = (const float*)d_in[2];  // (8,)
    float* out = (float*)d_out;

    float* meansbuf = (float*)d_ws;                      // 32*64*8 floats = 64 KB
    int*   done     = (int*)((char*)d_ws + 65536);       // 32 * 128-B lines = 4 KB

    hipMemsetAsync(d_ws, 0, 65536 + 4096, stream);       // graph-captured, per-replay

    se_fused_kernel<<<NBLK, 256, 0, stream>>>(x, W, bias, meansbuf, done, out);
}

// Round 11
// 94.405 us; speedup vs baseline: 1.6221x; 1.6221x over previous
//
#include <hip/hip_runtime.h>

#define HW    3136   // 56*56
#define HW4   784    // float4 per row = 12*64 + 16
#define C     512
#define B     32
#define ROWS  (B * C)   // 16384

typedef float floatx4 __attribute__((ext_vector_type(4)));

// Pass 1: one wave per (b,c) row (unchanged from round 8).
__global__ __launch_bounds__(256) void se_mean_kernel(const float* __restrict__ x,
                                                      float* __restrict__ y) {
    const int wave = threadIdx.x >> 6;
    const int lane = threadIdx.x & 63;
    const int row  = blockIdx.x * 4 + wave;   // [0, 16384)
    const floatx4* xr = reinterpret_cast<const floatx4*>(x) + (size_t)row * HW4;

    float s = 0.f;
    #pragma unroll
    for (int k = 0; k < 12; ++k) {            // 12*64 = 768 float4, uniform
        floatx4 v = xr[lane + 64 * k];
        s += (v.x + v.y) + (v.z + v.w);
    }
    if (lane < 16) {                          // float4 768..783
        floatx4 v = xr[768 + lane];
        s += (v.x + v.y) + (v.z + v.w);
    }
    #pragma unroll
    for (int off = 32; off; off >>= 1) s += __shfl_down(s, off, 64);
    if (lane == 0) y[row] = s * (1.0f / HW);
}

// Pass 2 A/B: one ROW per wave, ALL 13 float4 loads issued into registers
// before any store — maximally decoupled read/write streams (tests
// issue-limited vs fabric-limited). Block = 4 consecutive rows (one batch,
// one modality since 4 | 64); reverse block order; nt stores (both proven).
__global__ __launch_bounds__(256) void se_scale_kernel(const float* __restrict__ x,
                                                       const float* __restrict__ y,
                                                       const float* __restrict__ W,
                                                       const float* __restrict__ bias,
                                                       float* __restrict__ out) {
    const int row0 = (gridDim.x - 1 - blockIdx.x) * 4;  // reverse order
    const int b    = row0 >> 9;
    const int m    = (row0 & (C - 1)) >> 6;
    const int wave = threadIdx.x >> 6;
    const int lane = threadIdx.x & 63;

    // gate: 512-length dot, 8 FMA per lane, butterfly so every lane has it
    const float* yb = y + b * C;
    const float* wm = W + m * C;
    float s = 0.f;
    #pragma unroll
    for (int i = 0; i < 8; ++i) s = fmaf(yb[lane + 64 * i], wm[lane + 64 * i], s);
    #pragma unroll
    for (int off = 32; off; off >>= 1) s += __shfl_xor(s, off, 64);
    s += bias[m];
    s = fmaxf(s, 0.f);                          // relu
    const float g = 1.0f / (1.0f + expf(-s));   // sigmoid

    // one row per wave: 13 loads -> scale -> 13 nt stores
    const int row = row0 + wave;
    const floatx4* xr  = reinterpret_cast<const floatx4*>(x) + (size_t)row * HW4;
    floatx4*      orow = reinterpret_cast<floatx4*>(out)     + (size_t)row * HW4;

    floatx4 v[13];
    #pragma unroll
    for (int k = 0; k < 12; ++k) v[k] = xr[lane + 64 * k];
    const bool tail = (lane < 16);
    if (tail) v[12] = xr[768 + lane];

    #pragma unroll
    for (int k = 0; k < 12; ++k) v[k] *= g;
    if (tail) v[12] *= g;

    #pragma unroll
    for (int k = 0; k < 12; ++k)
        __builtin_nontemporal_store(v[k], &orow[lane + 64 * k]);
    if (tail)
        __builtin_nontemporal_store(v[12], &orow[768 + lane]);
}

extern "C" void kernel_launch(void* const* d_in, const int* in_sizes, int n_in,
                              void* d_out, int out_size, void* d_ws, size_t ws_size,
                              hipStream_t stream) {
    const float* x    = (const float*)d_in[0];  // (32,512,56,56)
    const float* W    = (const float*)d_in[1];  // (8,512)
    const float* bias = (const float*)d_in[2];  // (8,)
    float* out = (float*)d_out;

    float* y = (float*)d_ws;                    // 16384 floats = 64 KB

    se_mean_kernel <<<ROWS / 4, 256, 0, stream>>>(x, y);
    se_scale_kernel<<<ROWS / 4, 256, 0, stream>>>(x, y, W, bias, out);
}